// Round 6
// baseline (836.122 us; speedup 1.0000x reference)
//
#include <hip/hip_runtime.h>
#include <cstdint>
#include <cstddef>

typedef _Float16 f16;
typedef _Float16 f16x4 __attribute__((ext_vector_type(4)));
typedef _Float16 f16x8 __attribute__((ext_vector_type(8)));
typedef float f32x4 __attribute__((ext_vector_type(4)));

// ---------------------------------------------------------------------------
// async global->LDS, 16B per lane. LDS dest is WAVE-UNIFORM base; HW writes
// lane i at base + i*16 (m97/m104 semantics).
// ---------------------------------------------------------------------------
__device__ __forceinline__ void gl2lds16(const void* g, void* l) {
  __builtin_amdgcn_global_load_lds(
      (const __attribute__((address_space(1))) void*)(uintptr_t)g,
      (__attribute__((address_space(3))) void*)(uintptr_t)l,
      16, 0, 0);
}

// Direct global->VGPR 16B load, inline asm: the compiler does not track it,
// so it inserts NO vmcnt for it; completion is guaranteed by OUR counted
// vmcnt at the next step top (the load is then older than the 2 kept slots).
__device__ __forceinline__ void gload16(f16x8* dst, const void* addr) {
  asm volatile("global_load_dwordx4 %0, %1, off"
               : "=&v"(*dst) : "v"(addr) : "memory");
}

// ---------------------------------------------------------------------------
// Weight prep via LDS-bounce transpose. Tile 32 o x 32 i per block.
// Wt[o][i*9+0] = sb[i,o]; Wt[o][i*9+1+g] = coef[i,o,g]*ss[i,o].
// ---------------------------------------------------------------------------
__global__ __launch_bounds__(256) void kan_prep2(
    const float* __restrict__ coef, const float* __restrict__ sb,
    const float* __restrict__ ss, f16* __restrict__ Wt,
    int out, int K9)
{
  __shared__ float s_sb[32][32];   // [i][o]
  __shared__ float s_ss[32][32];
  __shared__ f16 s_w[32][288];     // [o][i*9+t]
  const int t  = threadIdx.x;
  const int o0 = blockIdx.x * 32, i0 = blockIdx.y * 32;

  {
    int il = t >> 3, oc = (t & 7) * 4;
    float4 vb = *(const float4*)(sb + (size_t)(i0 + il) * out + o0 + oc);
    float4 vs = *(const float4*)(ss + (size_t)(i0 + il) * out + o0 + oc);
    s_sb[il][oc + 0] = vb.x; s_sb[il][oc + 1] = vb.y;
    s_sb[il][oc + 2] = vb.z; s_sb[il][oc + 3] = vb.w;
    s_ss[il][oc + 0] = vs.x; s_ss[il][oc + 1] = vs.y;
    s_ss[il][oc + 2] = vs.z; s_ss[il][oc + 3] = vs.w;
  }
  __syncthreads();

#pragma unroll
  for (int j = 0; j < 8; ++j) {
    int f  = j * 256 + t;
    int il = f >> 6, c = f & 63;
    int ol = c >> 1, gh = (c & 1) * 4;
    float4 v = *(const float4*)(coef + ((size_t)(i0 + il) * out + (o0 + ol)) * 8 + gh);
    float ssv = s_ss[il][ol];
    f16* dst = &s_w[ol][il * 9 + 1 + gh];
    dst[0] = (f16)(v.x * ssv); dst[1] = (f16)(v.y * ssv);
    dst[2] = (f16)(v.z * ssv); dst[3] = (f16)(v.w * ssv);
  }
#pragma unroll
  for (int j = 0; j < 4; ++j) {
    int e = j * 256 + t; int il = e >> 5, ol = e & 31;
    s_w[ol][il * 9] = (f16)s_sb[il][ol];
  }
  __syncthreads();

  {
    int o = t >> 3, part = t & 7;
    f16* dst = Wt + (size_t)(o0 + o) * K9 + (size_t)i0 * 9 + part * 36;
    const f16* src = &s_w[o][part * 36];
#pragma unroll
    for (int q = 0; q < 9; ++q)
      *(f16x4*)(dst + q * 4) = *(const f16x4*)(src + q * 4);
  }
}

// ---------------------------------------------------------------------------
// Features: per x -> [silu(x), B3_0(x)..B3_7(x)] fp16, row-major F[b][i*9+t].
// Uniform pykan grid hardcoded: t_j = (j-3)*0.4 - 1.
// ---------------------------------------------------------------------------
__global__ __launch_bounds__(256) void kan_feat(
    const float* __restrict__ X, f16* __restrict__ F,
    int shift, int K9, int iBase)
{
  int idx = blockIdx.x * 256 + threadIdx.x;
  int b  = idx >> shift;
  int ii = idx & ((1 << shift) - 1);
  float x = X[idx];

  float sig  = 1.0f / (1.0f + __expf(-x));
  float silu = x * sig;

  float t[12];
#pragma unroll
  for (int j = 0; j < 12; ++j) t[j] = (float)(j - 3) * 0.4f - 1.0f;
  float b0[11];
#pragma unroll
  for (int j = 0; j < 11; ++j)
    b0[j] = (x >= t[j] && x < t[j + 1]) ? 1.0f : 0.0f;
  float b1[10];
#pragma unroll
  for (int j = 0; j < 10; ++j)
    b1[j] = (x - t[j]) * 2.5f * b0[j] + (t[j + 2] - x) * 2.5f * b0[j + 1];
  float b2[9];
#pragma unroll
  for (int j = 0; j < 9; ++j)
    b2[j] = (x - t[j]) * 1.25f * b1[j] + (t[j + 3] - x) * 1.25f * b1[j + 1];
  float b3[8];
#pragma unroll
  for (int j = 0; j < 8; ++j)
    b3[j] = (x - t[j]) * (1.0f / 1.2f) * b2[j] +
            (t[j + 4] - x) * (1.0f / 1.2f) * b2[j + 1];

  f16* o = F + (size_t)b * K9 + (size_t)(iBase + ii) * 9;
  o[0] = (f16)silu;
#pragma unroll
  for (int g = 0; g < 8; ++g) o[1 + g] = (f16)b3[g];
}

// ---------------------------------------------------------------------------
// GEMM: C[M,N] += A[M,K] * Bt[N,K]^T, fp16 in / fp32 out.
// A-DIRECT-TO-REGISTER / B-only-LDS. Block 128x128, BK=32, 4 waves (2x2),
// wave tile 64x64, acc[4][4].
// R5 post-mortem: all six schedule/occupancy variants pinned at ~16 cy per
// MFMA per CU; round time ~= ds_read burst (64KB/85Bcy) + DMA LDS-writes +
// MFMA, serialized by phase-locked waves. Fix = delete A's LDS path:
//  - af[mi] loaded global->VGPR via inline-asm dwordx4 (per-lane 16B K-slice,
//    identical fragment data as before). Removes A staging + A LDS-writes +
//    A's 2x-amplified ds_reads (-50% LDS pipe time, -50% DMA demand).
//  - B keeps the verified gl2lds + source-swizzle + LDS path (B is shared by
//    both waveM rows; chunk^=((row>>1)&3), 0 conflicts R0-R5).
//  - B ring-4 slots (8KB each) = 32KB LDS -> 3 blocks/CU (launch_bounds 3,
//    ~145 VGPR), cross-block overlap one better than R0's 2.
// vmcnt ledger (order pinned by sched_barrier(0) between groups):
//   step t issues [A(t+1) x4] then [B(t+2) x2]. At top of step s, in flight:
//   B(s)2 (from s-2), A(s)4 + B(s+1)2 (from s-1). vmcnt(2) drains B(s)+A(s),
//   keeps B(s+1) flying -> loads get a full step (~1500cy) of cover.
//   s >= kSteps-2: vmcnt(0). Prologue order B(0),A(0),B(1) sets the invariant.
// Rule #18: one sched_barrier(0) after each barrier (and between issue
// groups) so MFMAs cannot hoist above the counted waits; no other pinning.
// Slot reuse: stage(s+2) into slot (s+2)&3 happens after barrier s; its last
// readers ran before barrier s-1. Two-barrier separation -> safe.
// ---------------------------------------------------------------------------
#define BARRIER() do { asm volatile("" ::: "memory"); \
    __builtin_amdgcn_s_barrier(); asm volatile("" ::: "memory"); } while (0)
#define VMC2()  asm volatile("s_waitcnt vmcnt(2)" ::: "memory")
#define VMC0()  asm volatile("s_waitcnt vmcnt(0)" ::: "memory")
#define SCHED0() __builtin_amdgcn_sched_barrier(0)

#define STG_B(tile) do { \
    f16* _d = Lb + (((tile) & 3) << 12); \
    size_t _ko = (size_t)(tile) * 32; \
    gl2lds16(gB[0] + _ko, _d + lB0); \
    gl2lds16(gB[1] + _ko, _d + lB1); } while (0)

#define LOAD_A(dst, t) do { _Pragma("unroll") \
    for (int _mi = 0; _mi < 4; ++_mi) \
      gload16(&dst[_mi], (const void*)(aRow[_mi] + (uint64_t)(t) * 64)); \
  } while (0)

#define STEP_BODY(AF, s) do { \
    if ((s) < kSteps - 2) VMC2(); else VMC0(); \
    BARRIER(); \
    SCHED0(); \
    if ((s) + 1 < kSteps) LOAD_A(AF##_nxt, (s) + 1); \
    SCHED0(); \
    if ((s) + 2 < kSteps) STG_B((s) + 2); \
    { const f16* bufB = Lb + (((s) & 3) << 12); \
      f16x8 bf[4]; \
      _Pragma("unroll") for (int ni = 0; ni < 4; ++ni) \
        bf[ni] = *(const f16x8*)(bufB + bOff[ni]); \
      _Pragma("unroll") for (int mi = 0; mi < 4; ++mi) \
      _Pragma("unroll") for (int ni = 0; ni < 4; ++ni) \
        acc[mi][ni] = __builtin_amdgcn_mfma_f32_16x16x32_f16( \
            AF##_cur[mi], bf[ni], acc[mi][ni], 0, 0, 0); \
    } } while (0)

template <int SPLITK>
__global__ __launch_bounds__(256, 3) void kan_gemm(
    const f16* __restrict__ A, const f16* __restrict__ Bt,
    float* __restrict__ C, int N, int K)
{
  __shared__ __align__(16) f16 Lb[4 * 4096];  // B ring-4: 4 slots x 128x32 f16
  const int tid   = threadIdx.x;
  const int lane  = tid & 63;
  const int w     = tid >> 6;
  const int waveM = w >> 1, waveN = w & 1;
  const int l16   = lane & 15, quad = lane >> 4;
  const size_t mBase = (size_t)blockIdx.y * 128;
  const size_t nBase = (size_t)blockIdx.x * 128;
  const int kChunk = K / SPLITK;
  const int k0     = blockIdx.z * kChunk;
  const int kSteps = kChunk >> 5;   // even for all our shapes

  // B staging: 512 chunks of 16B (2/thread), source-swizzled (R0-verified).
  const f16* gB[2];
  {
    int g0 = tid,       r0 = g0 >> 2, c0 = (g0 & 3) ^ ((r0 >> 1) & 3);
    int g1 = 256 + tid, r1 = g1 >> 2, c1 = (g1 & 3) ^ ((r1 >> 1) & 3);
    gB[0] = Bt + (nBase + r0) * (size_t)K + k0 + c0 * 8;
    gB[1] = Bt + (nBase + r1) * (size_t)K + k0 + c1 * 8;
  }
  const int lB0 = (tid & ~63) * 8;
  const int lB1 = (256 + (tid & ~63)) * 8;

  // B fragment read offsets within a slot (f16 units).
  int bOff[4];
#pragma unroll
  for (int ni = 0; ni < 4; ++ni) {
    int col = waveN * 64 + ni * 16 + l16;
    bOff[ni] = col * 32 + (quad ^ ((col >> 1) & 3)) * 8;
  }

  // A fragment row base addresses (bytes); step t adds t*64.
  uint64_t aRow[4];
#pragma unroll
  for (int mi = 0; mi < 4; ++mi)
    aRow[mi] = (uint64_t)(const void*)(
        A + (mBase + (size_t)waveM * 64 + mi * 16 + l16) * (size_t)K
          + k0 + quad * 8);

  f32x4 acc[4][4] = {};
  f16x8 afA_cur[4], afA_nxt[4];
  // map: even step consumes afA_cur, loads into afA_nxt; odd step swapped.
  // Implemented with two explicit names to keep all indexing static.
#define afB_cur afA_nxt
#define afB_nxt afA_cur

  // prologue (order pinned: B0, A0, B1 -> vmcnt(2) at step0 keeps B1)
  STG_B(0);
  SCHED0();
  LOAD_A(afA_cur, 0);
  SCHED0();
  STG_B(1);

#pragma unroll 1
  for (int it = 0; it < (kSteps >> 1); ++it) {
    const int s0 = it * 2;
    STEP_BODY(afA, s0);      // consumes afA_cur, prefetches afA_nxt
    STEP_BODY(afB, s0 + 1);  // consumes afA_nxt, prefetches afA_cur
  }
#undef afB_cur
#undef afB_nxt

#pragma unroll
  for (int mi = 0; mi < 4; ++mi) {
    size_t row = mBase + waveM * 64 + mi * 16 + quad * 4;
#pragma unroll
    for (int ni = 0; ni < 4; ++ni) {
      size_t col = nBase + waveN * 64 + ni * 16 + l16;
#pragma unroll
      for (int r = 0; r < 4; ++r)
        unsafeAtomicAdd(C + (row + r) * N + col, acc[mi][ni][r]);
    }
  }
}

// ---------------------------------------------------------------------------
// Orchestration. WS: Wt (18.9MB) | F (75.5MB) | actA | actB (16.8MB each).
// All GEMM grids = 768 blocks -> exactly 3 resident/CU (32KB LDS, ~145 VGPR,
// launch_bounds(256,3)), every block co-resident, no dispatch tail.
// ---------------------------------------------------------------------------
extern "C" void kernel_launch(void* const* d_in, const int* in_sizes, int n_in,
                              void* d_out, int out_size, void* d_ws, size_t ws_size,
                              hipStream_t stream)
{
  const float* y = (const float*)d_in[0];
  const float* u = (const float*)d_in[1];
  const float* coef[4]; const float* sb[4]; const float* ss[4];
  for (int l = 0; l < 4; ++l) {
    coef[l] = (const float*)d_in[2 + 4 * l];
    sb[l]   = (const float*)d_in[3 + 4 * l];
    ss[l]   = (const float*)d_in[4 + 4 * l];
  }
  char* ws = (char*)d_ws;
  f16*   Wt   = (f16*)(ws);
  f16*   F    = (f16*)(ws + 18874368);                        // 9216*1024*2
  float* actA = (float*)(ws + 18874368 + 75497472);           // + 4096*9216*2
  float* actB = (float*)(ws + 18874368 + 75497472 + 16777216);
  float* out  = (float*)d_out;
  const size_t actBytes = (size_t)4096 * 1024 * 4;

  // Layer 0: in=512 (concat y|u), out=1024, K=4608. splitK=3 (kSteps 48).
  kan_prep2<<<dim3(32, 16), 256, 0, stream>>>(coef[0], sb[0], ss[0], Wt, 1024, 4608);
  kan_feat<<<4096 * 256 / 256, 256, 0, stream>>>(y, F, 8, 4608, 0);
  kan_feat<<<4096 * 256 / 256, 256, 0, stream>>>(u, F, 8, 4608, 256);
  hipMemsetAsync(actA, 0, actBytes, stream);
  kan_gemm<3><<<dim3(8, 32, 3), 256, 0, stream>>>(F, Wt, actA, 1024, 4608);

  // Layer 1: in=1024, out=1024, K=9216. splitK=3 (kSteps 96).
  kan_prep2<<<dim3(32, 32), 256, 0, stream>>>(coef[1], sb[1], ss[1], Wt, 1024, 9216);
  kan_feat<<<4096 * 1024 / 256, 256, 0, stream>>>(actA, F, 10, 9216, 0);
  hipMemsetAsync(actB, 0, actBytes, stream);
  kan_gemm<3><<<dim3(8, 32, 3), 256, 0, stream>>>(F, Wt, actB, 1024, 9216);

  // Layer 2: in=1024, out=1024, K=9216. splitK=3.
  kan_prep2<<<dim3(32, 32), 256, 0, stream>>>(coef[2], sb[2], ss[2], Wt, 1024, 9216);
  kan_feat<<<4096 * 1024 / 256, 256, 0, stream>>>(actB, F, 10, 9216, 0);
  hipMemsetAsync(actA, 0, actBytes, stream);
  kan_gemm<3><<<dim3(8, 32, 3), 256, 0, stream>>>(F, Wt, actA, 1024, 9216);

  // Layer 3: in=1024, out=256, K=9216. splitK=12 -> 768 blocks (kSteps 24).
  kan_prep2<<<dim3(8, 32), 256, 0, stream>>>(coef[3], sb[3], ss[3], Wt, 256, 9216);
  kan_feat<<<4096 * 1024 / 256, 256, 0, stream>>>(actA, F, 10, 9216, 0);
  hipMemsetAsync(d_out, 0, (size_t)out_size * sizeof(float), stream);
  kan_gemm<12><<<dim3(2, 32, 12), 256, 0, stream>>>(F, Wt, out, 256, 9216);
}

// Round 7
// 590.933 us; speedup vs baseline: 1.4149x; 1.4149x over previous
//
#include <hip/hip_runtime.h>
#include <cstdint>
#include <cstddef>

typedef _Float16 f16;
typedef _Float16 f16x2 __attribute__((ext_vector_type(2)));
typedef _Float16 f16x4 __attribute__((ext_vector_type(4)));
typedef _Float16 f16x8 __attribute__((ext_vector_type(8)));
typedef float f32x4 __attribute__((ext_vector_type(4)));

// ---------------------------------------------------------------------------
// async global->LDS, 16B per lane. LDS dest is WAVE-UNIFORM base; HW writes
// lane i at base + i*16 (m97/m104 semantics).
// ---------------------------------------------------------------------------
__device__ __forceinline__ void gl2lds16(const void* g, void* l) {
  __builtin_amdgcn_global_load_lds(
      (const __attribute__((address_space(1))) void*)(uintptr_t)g,
      (__attribute__((address_space(3))) void*)(uintptr_t)l,
      16, 0, 0);
}

// ---------------------------------------------------------------------------
// B-spline features for one x: out9 = [silu, B3_0..B3_7].
// Uniform pykan grid hardcoded: t_j = (j-3)*0.4 - 1.
// ---------------------------------------------------------------------------
__device__ __forceinline__ void kan_basis(float x, f16* out9) {
  float sig  = 1.0f / (1.0f + __expf(-x));
  out9[0] = (f16)(x * sig);

  float t[12];
#pragma unroll
  for (int j = 0; j < 12; ++j) t[j] = (float)(j - 3) * 0.4f - 1.0f;
  float b0[11];
#pragma unroll
  for (int j = 0; j < 11; ++j)
    b0[j] = (x >= t[j] && x < t[j + 1]) ? 1.0f : 0.0f;
  float b1[10];
#pragma unroll
  for (int j = 0; j < 10; ++j)
    b1[j] = (x - t[j]) * 2.5f * b0[j] + (t[j + 2] - x) * 2.5f * b0[j + 1];
  float b2[9];
#pragma unroll
  for (int j = 0; j < 9; ++j)
    b2[j] = (x - t[j]) * 1.25f * b1[j] + (t[j + 3] - x) * 1.25f * b1[j + 1];
#pragma unroll
  for (int j = 0; j < 8; ++j)
    out9[1 + j] = (f16)((x - t[j]) * (1.0f / 1.2f) * b2[j] +
                        (t[j + 4] - x) * (1.0f / 1.2f) * b2[j + 1]);
}

// ---------------------------------------------------------------------------
// MERGED prep+feat kernel (R7: fuse launches; non-GEMM was ~290us = 47% of
// the budget, invisible in top-5 counters).
// K-layout is now T-MAJOR: k = t*din + i  (t=0: silu/base, t=1+g: spline g).
// Both F and Wt use it -> GEMM is unchanged (same products, reordered K-sum).
//
// Blocks [0, prepBlocks): weight prep, tile 32 o x 32 i.
//   Wt[o][0*din+i] = sb[i,o]; Wt[o][(1+g)*din+i] = coef[i,o,g]*ss[i,o].
// Blocks [prepBlocks, ...): features, 2 inputs/thread, f16x2 plane stores ->
//   9 fully-coalesced dword stores/thread (was 9 scattered scalar-f16 stores,
//   the suspected ~40-70us/dispatch killer).
//   seg 0 reads Xa, seg 1 reads Xb (L0's y|u concat); X row stride = segW.
// ---------------------------------------------------------------------------
__global__ __launch_bounds__(256) void kan_prep_feat(
    const float* __restrict__ coef, const float* __restrict__ sb,
    const float* __restrict__ ss, f16* __restrict__ Wt,
    const float* __restrict__ Xa, const float* __restrict__ Xb,
    f16* __restrict__ F,
    int dout, int din, int prepBlocks, int featB, int segW, int bShift)
{
  __shared__ float s_sb[32][32];   // [i][o]
  __shared__ float s_ss[32][32];
  __shared__ f16 s_w[32][288];     // [o][i*9+t]
  const int t = threadIdx.x;
  const int gid = blockIdx.x;
  const int K9 = 9 * din;

  if (gid < prepBlocks) {
    const int prepBX = dout >> 5;
    const int o0 = (gid % prepBX) * 32, i0 = (gid / prepBX) * 32;

    {
      int il = t >> 3, oc = (t & 7) * 4;
      float4 vb = *(const float4*)(sb + (size_t)(i0 + il) * dout + o0 + oc);
      float4 vs = *(const float4*)(ss + (size_t)(i0 + il) * dout + o0 + oc);
      s_sb[il][oc + 0] = vb.x; s_sb[il][oc + 1] = vb.y;
      s_sb[il][oc + 2] = vb.z; s_sb[il][oc + 3] = vb.w;
      s_ss[il][oc + 0] = vs.x; s_ss[il][oc + 1] = vs.y;
      s_ss[il][oc + 2] = vs.z; s_ss[il][oc + 3] = vs.w;
    }
    __syncthreads();

#pragma unroll
    for (int j = 0; j < 8; ++j) {
      int f  = j * 256 + t;
      int il = f >> 6, c = f & 63;
      int ol = c >> 1, gh = (c & 1) * 4;
      float4 v = *(const float4*)(coef + ((size_t)(i0 + il) * dout + (o0 + ol)) * 8 + gh);
      float ssv = s_ss[il][ol];
      f16* dst = &s_w[ol][il * 9 + 1 + gh];
      dst[0] = (f16)(v.x * ssv); dst[1] = (f16)(v.y * ssv);
      dst[2] = (f16)(v.z * ssv); dst[3] = (f16)(v.w * ssv);
    }
#pragma unroll
    for (int j = 0; j < 4; ++j) {
      int e = j * 256 + t; int il = e >> 5, ol = e & 31;
      s_w[ol][il * 9] = (f16)s_sb[il][ol];
    }
    __syncthreads();

    {  // t-major writeout: per (o,part), 9 planes x f16x4
      int o = t >> 3, part = t & 7;
      f16* dstRow = Wt + (size_t)(o0 + o) * K9 + i0 + part * 4;
#pragma unroll
      for (int tp = 0; tp < 9; ++tp) {
        f16x4 v;
#pragma unroll
        for (int j = 0; j < 4; ++j) v[j] = s_w[o][(part * 4 + j) * 9 + tp];
        *(f16x4*)(dstRow + (size_t)tp * din) = v;
      }
    }
    return;
  }

  // ---- feature branch ----
  int f   = gid - prepBlocks;
  int seg = (f >= featB) ? 1 : 0;
  int fi  = f - seg * featB;
  const float* X = seg ? Xb : Xa;
  const int halfW = segW >> 1;
  int idx2 = fi * 256 + t;
  int b  = idx2 >> bShift;
  int ii = idx2 & (halfW - 1);
  int i  = seg * segW + 2 * ii;

  float2 xv = *(const float2*)(X + (size_t)b * segW + 2 * ii);
  f16 s0[9], s1[9];
  kan_basis(xv.x, s0);
  kan_basis(xv.y, s1);

  f16* o = F + (size_t)b * K9 + i;
#pragma unroll
  for (int tp = 0; tp < 9; ++tp) {
    f16x2 v; v[0] = s0[tp]; v[1] = s1[tp];
    *(f16x2*)(o + (size_t)tp * din) = v;
  }
}

// ---------------------------------------------------------------------------
// GEMM: C[M,N] += A[M,K] * Bt[N,K]^T, fp16 in / fp32 out.  (R0 VERBATIM —
// best measured config: 120us big-GEMM, MfmaUtil 27%, 0 conflicts.)
// Block 128x128, BK=32, 4 waves (2x2), wave tile 64x64, acc[4][4].
// RING-4 PIPELINE, issue-ahead 3. Steady state per step: s_waitcnt vmcnt(8)
// [step-s's 4 loads done; s+1,s+2 in flight]; s_barrier; issue step-s+3 into
// buf freed by this barrier; ds_read frags; 16 MFMA.
// XOR swizzle chunk^=((row>>1)&3) at source: verified 0 conflicts.
// LDS 64KB -> exactly 2 blocks/CU; grids sized 512 so all co-resident.
// ---------------------------------------------------------------------------
template <int SPLITK>
__global__ __launch_bounds__(256, 2) void kan_gemm(
    const f16* __restrict__ A, const f16* __restrict__ Bt,
    float* __restrict__ C, int N, int K)
{
  __shared__ __align__(16) f16 lds[4][8192];  // ring: [buf][ A:128x32 | B:128x32 ]
  const int tid   = threadIdx.x;
  const int lane  = tid & 63;
  const int w     = tid >> 6;
  const int waveM = w >> 1, waveN = w & 1;
  const int l16   = lane & 15, quad = lane >> 4;
  const size_t mBase = (size_t)blockIdx.y * 128;
  const size_t nBase = (size_t)blockIdx.x * 128;
  const int kChunk = K / SPLITK;
  const int k0     = blockIdx.z * kChunk;
  const int kSteps = kChunk >> 5;

  // staging: A = 512 chunks of 16B (2/thread), B same. Swizzled at source.
  const f16* gA[2]; int lA[2];
  const f16* gB[2]; int lB[2];
#pragma unroll
  for (int r = 0; r < 2; ++r) {
    int g = r * 256 + tid, row = g >> 2;
    int cs = (g & 3) ^ ((row >> 1) & 3);
    gA[r] = A + (mBase + row) * (size_t)K + k0 + cs * 8;
    gB[r] = Bt + (nBase + row) * (size_t)K + k0 + cs * 8;
    lA[r] = (r * 256 + (tid & ~63)) * 8;
    lB[r] = 4096 + lA[r];
  }

  f32x4 acc[4][4] = {};

  // preload steps 0..2 into bufs 0..2 (kSteps >= 36 in all our shapes)
#pragma unroll
  for (int p = 0; p < 3; ++p) {
    f16* b = lds[p];
    int kk = p * 32;
#pragma unroll
    for (int r = 0; r < 2; ++r) {
      gl2lds16(gA[r] + kk, b + lA[r]);
      gl2lds16(gB[r] + kk, b + lB[r]);
    }
  }

  for (int s = 0; s < kSteps; ++s) {
    // drain step-s's 4 loads only; keep later steps in flight (tail: fewer)
    if (s < kSteps - 2)       asm volatile("s_waitcnt vmcnt(8)" ::: "memory");
    else if (s == kSteps - 2) asm volatile("s_waitcnt vmcnt(4)" ::: "memory");
    else                      asm volatile("s_waitcnt vmcnt(0)" ::: "memory");
    __builtin_amdgcn_s_barrier();

    if (s + 3 < kSteps) {  // refill the buffer freed by the barrier above
      int kk = (s + 3) * 32;
      f16* b = lds[(s + 3) & 3];
#pragma unroll
      for (int r = 0; r < 2; ++r) {
        gl2lds16(gA[r] + kk, b + lA[r]);
        gl2lds16(gB[r] + kk, b + lB[r]);
      }
    }

    const f16* buf = lds[s & 3];
    f16x8 af[4], bf[4];
#pragma unroll
    for (int mi = 0; mi < 4; ++mi) {
      int row = waveM * 64 + mi * 16 + l16;
      af[mi] = *(const f16x8*)(buf + row * 32 + (quad ^ ((row >> 1) & 3)) * 8);
    }
#pragma unroll
    for (int ni = 0; ni < 4; ++ni) {
      int col = waveN * 64 + ni * 16 + l16;
      bf[ni] = *(const f16x8*)(buf + 4096 + col * 32 + (quad ^ ((col >> 1) & 3)) * 8);
    }
#pragma unroll
    for (int mi = 0; mi < 4; ++mi)
#pragma unroll
      for (int ni = 0; ni < 4; ++ni)
        acc[mi][ni] = __builtin_amdgcn_mfma_f32_16x16x32_f16(
            af[mi], bf[ni], acc[mi][ni], 0, 0, 0);
  }

#pragma unroll
  for (int mi = 0; mi < 4; ++mi) {
    size_t row = mBase + waveM * 64 + mi * 16 + quad * 4;
#pragma unroll
    for (int ni = 0; ni < 4; ++ni) {
      size_t col = nBase + waveN * 64 + ni * 16 + l16;
#pragma unroll
      for (int r = 0; r < 4; ++r)
        unsafeAtomicAdd(C + (row + r) * N + col, acc[mi][ni][r]);
    }
  }
}

// ---------------------------------------------------------------------------
// Orchestration. WS: Wt (18.9MB) | F (75.5MB) | actA | actB (16.8MB each).
// R7: 11 launches (was 17): 2 upfront memsets (actA+actB fused: contiguous),
// 1 mid memset (actA re-zero for L2), 4 merged prep+feat, 4 GEMMs.
// GEMM grids = 512 blocks -> exactly 2 resident/CU, no dispatch tail.
// ---------------------------------------------------------------------------
extern "C" void kernel_launch(void* const* d_in, const int* in_sizes, int n_in,
                              void* d_out, int out_size, void* d_ws, size_t ws_size,
                              hipStream_t stream)
{
  const float* y = (const float*)d_in[0];
  const float* u = (const float*)d_in[1];
  const float* coef[4]; const float* sb[4]; const float* ss[4];
  for (int l = 0; l < 4; ++l) {
    coef[l] = (const float*)d_in[2 + 4 * l];
    sb[l]   = (const float*)d_in[3 + 4 * l];
    ss[l]   = (const float*)d_in[4 + 4 * l];
  }
  char* ws = (char*)d_ws;
  f16*   Wt   = (f16*)(ws);
  f16*   F    = (f16*)(ws + 18874368);                        // 9216*1024*2
  float* actA = (float*)(ws + 18874368 + 75497472);           // + 4096*9216*2
  float* actB = (float*)(ws + 18874368 + 75497472 + 16777216);
  float* out  = (float*)d_out;
  const size_t actBytes = (size_t)4096 * 1024 * 4;

  // upfront zeroing: actA|actB contiguous in one call; out separately.
  hipMemsetAsync(actA, 0, 2 * actBytes, stream);
  hipMemsetAsync(d_out, 0, (size_t)out_size * sizeof(float), stream);

  // Layer 0: in=512 (y|u), out=1024, K=4608. prep 512 blocks; feat 2 segs
  // of 2048 blocks (segW=256, halfW=128 -> bShift 7). splitK=2 (kSteps 72).
  kan_prep_feat<<<512 + 4096, 256, 0, stream>>>(
      coef[0], sb[0], ss[0], Wt, y, u, F, 1024, 512, 512, 2048, 256, 7);
  kan_gemm<2><<<dim3(8, 32, 2), 256, 0, stream>>>(F, Wt, actA, 1024, 4608);

  // Layer 1: in=1024, out=1024, K=9216. prep 1024; feat 8192 (bShift 9).
  kan_prep_feat<<<1024 + 8192, 256, 0, stream>>>(
      coef[1], sb[1], ss[1], Wt, actA, nullptr, F, 1024, 1024, 1024, 8192, 1024, 9);
  kan_gemm<2><<<dim3(8, 32, 2), 256, 0, stream>>>(F, Wt, actB, 1024, 9216);

  // re-zero actA (L2 output; actA last read by L1's feat above)
  hipMemsetAsync(actA, 0, actBytes, stream);

  // Layer 2: in=1024, out=1024, K=9216.
  kan_prep_feat<<<1024 + 8192, 256, 0, stream>>>(
      coef[2], sb[2], ss[2], Wt, actB, nullptr, F, 1024, 1024, 1024, 8192, 1024, 9);
  kan_gemm<2><<<dim3(8, 32, 2), 256, 0, stream>>>(F, Wt, actA, 1024, 9216);

  // Layer 3: in=1024, out=256, K=9216. prep 256 blocks; splitK=8 (kSteps 36).
  kan_prep_feat<<<256 + 8192, 256, 0, stream>>>(
      coef[3], sb[3], ss[3], Wt, actA, nullptr, F, 256, 1024, 256, 8192, 1024, 9);
  kan_gemm<8><<<dim3(2, 32, 8), 256, 0, stream>>>(F, Wt, out, 256, 9216);
}